// Round 14
// baseline (114.371 us; speedup 1.0000x reference)
//
#include <hip/hip_runtime.h>

typedef __bf16 bf16;
typedef __attribute__((ext_vector_type(4))) bf16 bf16x4;
typedef __attribute__((ext_vector_type(8))) bf16 bf16x8;
typedef __attribute__((ext_vector_type(4))) float f32x4;

#define MFMA16(a, b, c) __builtin_amdgcn_mfma_f32_16x16x32_bf16(a, b, c, 0, 0, 0)
#define EXP2F(x) __builtin_amdgcn_exp2f(x)

constexpr int Bb = 4, Ss = 4096, Ee = 1024, Hh = 128;
constexpr int Mrows = Bb * Ss;  // 16384
constexpr int QB = 128;         // attn q-block
constexpr int NQB = Ss / QB;    // 32

// ---------------------------------------------------------------------------
// Kernel 0: build fragment-major Wfrag DIRECTLY from W (no Wt intermediate).
// Wfrag[((S*32 + ks)*64 + lane)*8 + j] = W_{S>>3}[ks*32 + (lane>>4)*8 + j]
//                                          [(S&7)*16 + (lane&15)]
// (one MFMA B-frag slice; a wave's load of frag (S,ks) is one coalesced 1KB
// read). grid 24 (=S), block 256.
// ---------------------------------------------------------------------------
__global__ __launch_bounds__(256) void wfrag_kernel(
    const float* __restrict__ Wq, const float* __restrict__ Wk,
    const float* __restrict__ Wv, bf16* __restrict__ Wfrag)
{
    __shared__ bf16 Sb[1024][18];   // [k][col], padded row = 36B (2-way free)
    const int S = blockIdx.x, t = threadIdx.x;
    const float* W = ((S >> 3) == 0) ? Wq : ((S >> 3) == 1) ? Wk : Wv;
    const int c0 = (S & 7) * 16;
    // phase 1: stage 16 cols x 1024 k as bf16 (each thread: 4 k-rows)
    #pragma unroll
    for (int j = 0; j < 4; ++j) {
        int k = t + 256 * j;
        const float4* src = (const float4*)(W + (size_t)k * Hh + c0);
        #pragma unroll
        for (int q = 0; q < 4; ++q) {
            float4 v = src[q];
            bf16x4 o; o[0] = (bf16)v.x; o[1] = (bf16)v.y; o[2] = (bf16)v.z; o[3] = (bf16)v.w;
            *(bf16x4*)&Sb[k][q * 4] = o;
        }
    }
    __syncthreads();
    // phase 2: emit fragments (coalesced 1KB per wave-write)
    const int lane = t & 63;
    #pragma unroll
    for (int r = 0; r < 8; ++r) {
        int ks = (t >> 6) + 4 * r;
        int kb = ks * 32 + (lane >> 4) * 8;
        bf16x8 o;
        #pragma unroll
        for (int j = 0; j < 8; ++j) o[j] = Sb[kb + j][lane & 15];
        *(bf16x8*)&Wfrag[(((size_t)S * 32 + ks) * 64 + lane) * 8] = o;
    }
}

// ---------------------------------------------------------------------------
// Kernel 1: fused QKV projection — A-resident bf16 panel + fragment-major B.
// grid (Mrows/32) = 512, block 512 (8 waves). Phase 1: stage 32x1024 embds
// f32 -> bf16 into chunk-XOR-swizzled LDS (one barrier). Phase 2: 32-step
// k-loop, ZERO barriers: 2 swizzled ds_read_b128 A-frags + 3 coalesced 1KB
// B loads (depth-2 reg prefetch) + 6 MFMA per step. Wave wv owns col-frags
// F = 3wv..3wv+2 (F>>3 = proj, (F&7)*16 = col).
// V written transposed: Vtg[b][h][s]. Q pre-scaled by log2(e)/sqrt(H)
// (exp2-domain softmax downstream).
// ---------------------------------------------------------------------------
__global__ __launch_bounds__(512, 4) void proj_kernel(
    const float* __restrict__ embds, const bf16* __restrict__ Wfrag,
    const float* __restrict__ bq, const float* __restrict__ bk,
    const float* __restrict__ bv,
    bf16* __restrict__ Qb, bf16* __restrict__ Kb, bf16* __restrict__ Vtg)
{
    __shared__ bf16 As[32][1024];   // 64 KB; 16B chunk c stored at c^(row&15)

    const int t = threadIdx.x;
    const int wv = t >> 6, lane = t & 63, lo = lane & 15, hi = lane >> 4;
    const int m0 = blockIdx.x * 32;

    // ---- phase 1: A panel f32 -> bf16, swizzled ----
    {
        const int row = t >> 4, cbc = (t & 15) * 8;
        const float4* src = (const float4*)(embds + (size_t)(m0 + row) * Ee + (t & 15) * 64);
        #pragma unroll
        for (int jj = 0; jj < 8; ++jj) {
            float4 v0 = src[2 * jj], v1 = src[2 * jj + 1];
            bf16x8 o;
            o[0] = (bf16)v0.x; o[1] = (bf16)v0.y; o[2] = (bf16)v0.z; o[3] = (bf16)v0.w;
            o[4] = (bf16)v1.x; o[5] = (bf16)v1.y; o[6] = (bf16)v1.z; o[7] = (bf16)v1.w;
            *(bf16x8*)&As[row][((cbc + jj) ^ (row & 15)) * 8] = o;
        }
    }
    __syncthreads();

    // ---- phase 2: barrier-free k-loop ----
    f32x4 acc[2][3];
    #pragma unroll
    for (int rg = 0; rg < 2; ++rg)
        #pragma unroll
        for (int f = 0; f < 3; ++f) acc[rg][f] = f32x4{0.f, 0.f, 0.f, 0.f};

    const bf16* bp0 = Wfrag + ((size_t)(wv * 3 + 0) * 32) * 512 + lane * 8;
    const bf16* bp1 = Wfrag + ((size_t)(wv * 3 + 1) * 32) * 512 + lane * 8;
    const bf16* bp2 = Wfrag + ((size_t)(wv * 3 + 2) * 32) * 512 + lane * 8;

    bf16x8 c0 = *(const bf16x8*)(bp0);
    bf16x8 c1 = *(const bf16x8*)(bp1);
    bf16x8 c2 = *(const bf16x8*)(bp2);
    bf16x8 n0 = *(const bf16x8*)(bp0 + 512);
    bf16x8 n1 = *(const bf16x8*)(bp1 + 512);
    bf16x8 n2 = *(const bf16x8*)(bp2 + 512);

    #pragma unroll
    for (int ks = 0; ks < 32; ++ks) {
        const int pos = ((ks * 4 + hi) ^ lo) * 8;
        bf16x8 a0 = *(const bf16x8*)&As[lo][pos];
        bf16x8 a1 = *(const bf16x8*)&As[16 + lo][pos];
        acc[0][0] = MFMA16(a0, c0, acc[0][0]);
        acc[1][0] = MFMA16(a1, c0, acc[1][0]);
        acc[0][1] = MFMA16(a0, c1, acc[0][1]);
        acc[1][1] = MFMA16(a1, c1, acc[1][1]);
        acc[0][2] = MFMA16(a0, c2, acc[0][2]);
        acc[1][2] = MFMA16(a1, c2, acc[1][2]);
        c0 = n0; c1 = n1; c2 = n2;
        if (ks + 2 < 32) {
            n0 = *(const bf16x8*)(bp0 + (ks + 2) * 512);
            n1 = *(const bf16x8*)(bp1 + (ks + 2) * 512);
            n2 = *(const bf16x8*)(bp2 + (ks + 2) * 512);
        }
    }

    // ---- epilogue: frag F -> proj/col; V transposed ----
    #pragma unroll
    for (int f = 0; f < 3; ++f) {
        const int F = wv * 3 + f;
        const int p = F >> 3;
        const int col = (F & 7) * 16 + lo;
        const float* bias = (p == 0) ? bq : (p == 1) ? bk : bv;
        float bvv = bias[col];
        if (p == 2) {
            const int mb = m0 >> 12, s0l = m0 & 4095;
            #pragma unroll
            for (int rg = 0; rg < 2; ++rg)
                #pragma unroll
                for (int i = 0; i < 4; ++i) {
                    int s = s0l + rg * 16 + hi * 4 + i;
                    Vtg[((size_t)mb * Hh + col) * Ss + s] = (bf16)(acc[rg][f][i] + bvv);
                }
        } else {
            bf16* dst = (p == 0) ? Qb : Kb;
            // Q scale = log2(e)/sqrt(128): softmax runs in exp2 domain
            const float scale = (p == 0) ? 0.1275174407017663f : 1.0f;
            #pragma unroll
            for (int rg = 0; rg < 2; ++rg)
                #pragma unroll
                for (int i = 0; i < 4; ++i) {
                    int row = m0 + rg * 16 + hi * 4 + i;
                    dst[(size_t)row * Hh + col] = (bf16)((acc[rg][f][i] + bvv) * scale);
                }
        }
    }
}

// ---------------------------------------------------------------------------
// Kernel 2: split-KV causal flash attention, swapped QK^T, QBLK=128,
// exp2-domain softmax + defer-max (THR=8) + packed P stores.
// grid (CH, B); block u covers qb with nchunks(qb) = ceil((2qb+2)/DIV)
// chunks of contiguous tiles. block 256 (4 waves x 32 q-rows, 2 q-groups).
// ---------------------------------------------------------------------------
__global__ __launch_bounds__(256, 2) void attn_kernel(
    const bf16* __restrict__ Qb, const bf16* __restrict__ Kb,
    const bf16* __restrict__ Vtg,
    float* __restrict__ Opart, float* __restrict__ Mpart, float* __restrict__ Lpart,
    int DIV, int CH)
{
    __shared__ bf16 Ks[64][136];   // K tile, stride 272B
    __shared__ bf16 Vt[128][64];   // V^T tile, (h&7)-XOR swizzled 16B chunks
    __shared__ bf16 Ps[4][32][72]; // wave-private P[q][kv], 2 q-groups

    const int t = threadIdx.x;
    const int wv = t >> 6, lane = t & 63, lo = lane & 15, hi = lane >> 4;
    const int slot = blockIdx.x, b = blockIdx.y;

    // decode slot -> (qb, chunk u of nch)
    int u = slot, qb = 0, nch = 1;
    for (qb = 0; qb < NQB; ++qb) {
        nch = (2 * qb + 2 + DIV - 1) / DIV;
        if (u < nch) break;
        u -= nch;
    }
    const int ntiles = 2 * qb + 2;
    const int t0 = (u * ntiles) / nch;
    const int t1 = ((u + 1) * ntiles) / nch;

    const int q0 = qb * QB;
    const size_t base = (size_t)b * Ss * Hh;
    const size_t vbase = (size_t)b * Hh * Ss;

    const bf16* kg = Kb + base + (size_t)(t >> 4) * Hh + (t & 15) * 8;
    const bf16* vg = Vtg + vbase + (size_t)(t >> 3) * Ss + (t & 7) * 8;
    bf16* ksl = &Ks[t >> 4][(t & 15) * 8];
    bf16* vsl = &Vt[t >> 3][((t & 7) * 8) ^ (((t >> 3) & 7) << 3)];

    bf16x8 qf[2][4];
    #pragma unroll
    for (int g = 0; g < 2; ++g)
        #pragma unroll
        for (int kk = 0; kk < 4; ++kk)
            qf[g][kk] = *(const bf16x8*)(
                Qb + base + (size_t)(q0 + wv * 32 + g * 16 + lo) * Hh + kk * 32 + hi * 8);

    f32x4 acc[2][8];
    #pragma unroll
    for (int g = 0; g < 2; ++g)
        #pragma unroll
        for (int f = 0; f < 8; ++f) acc[g][f] = f32x4{0.f, 0.f, 0.f, 0.f};
    float M_[2] = {-1e30f, -1e30f};   // finite: fully-masked tiles stay NaN-free
    float L_[2] = {0.f, 0.f};

    uint4 kr0, kr1, kr2, kr3, vr0, vr1, vr2, vr3;
#define ISSUE(T) do {                                            \
        const bf16* kp_ = kg + (size_t)(T) * (64 * Hh);          \
        kr0 = *(const uint4*)(kp_);                              \
        kr1 = *(const uint4*)(kp_ + 16 * Hh);                    \
        kr2 = *(const uint4*)(kp_ + 32 * Hh);                    \
        kr3 = *(const uint4*)(kp_ + 48 * Hh);                    \
        const bf16* vp_ = vg + (T) * 64;                         \
        vr0 = *(const uint4*)(vp_);                              \
        vr1 = *(const uint4*)(vp_ + 32 * Ss);                    \
        vr2 = *(const uint4*)(vp_ + 64 * Ss);                    \
        vr3 = *(const uint4*)(vp_ + 96 * Ss);                    \
    } while (0)

    ISSUE(t0);
    for (int tile = t0; tile < t1; ++tile) {
        __syncthreads();   // previous tile's LDS reads done
        *(uint4*)(ksl) = kr0;
        *(uint4*)(ksl + 16 * 136) = kr1;
        *(uint4*)(ksl + 32 * 136) = kr2;
        *(uint4*)(ksl + 48 * 136) = kr3;
        *(uint4*)(vsl) = vr0;
        *(uint4*)(vsl + 32 * 64) = vr1;
        *(uint4*)(vsl + 64 * 64) = vr2;
        *(uint4*)(vsl + 96 * 64) = vr3;
        if (tile + 1 < t1) ISSUE(tile + 1);
        __syncthreads();
        const int kv0 = tile * 64;

        // S^T = K Q^T per q-group: D[kv][q], kv = f*16+hi*4+i, q = lo
        f32x4 sv[2][4];
        #pragma unroll
        for (int g = 0; g < 2; ++g)
            #pragma unroll
            for (int f = 0; f < 4; ++f) sv[g][f] = f32x4{0.f, 0.f, 0.f, 0.f};
        __builtin_amdgcn_s_setprio(1);
        #pragma unroll
        for (int kk = 0; kk < 4; ++kk) {
            #pragma unroll
            for (int f = 0; f < 4; ++f) {
                bf16x8 kf = *(const bf16x8*)&Ks[f * 16 + lo][kk * 32 + hi * 8];
                sv[0][f] = MFMA16(kf, qf[0][kk], sv[0][f]);
                sv[1][f] = MFMA16(kf, qf[1][kk], sv[1][f]);
            }
        }
        __builtin_amdgcn_s_setprio(0);

        #pragma unroll
        for (int g = 0; g < 2; ++g) {
            const int qg0 = q0 + wv * 32 + g * 16;   // wave-uniform per g
            if (kv0 + 63 > qg0) {                    // masking needed
                int qg = qg0 + lo;
                #pragma unroll
                for (int f = 0; f < 4; ++f)
                    #pragma unroll
                    for (int i = 0; i < 4; ++i)
                        if (kv0 + f * 16 + hi * 4 + i > qg) sv[g][f][i] = -INFINITY;
            }
            // row max (lane owns 16 kv of row q=lo): in-lane tree + 2 shuffles
            float pm = -INFINITY;
            #pragma unroll
            for (int f = 0; f < 4; ++f)
                pm = fmaxf(pm, fmaxf(fmaxf(sv[g][f][0], sv[g][f][1]),
                                     fmaxf(sv[g][f][2], sv[g][f][3])));
            pm = fmaxf(pm, __shfl_xor(pm, 16));
            pm = fmaxf(pm, __shfl_xor(pm, 32));
            // defer-max: rescale only when pm exceeds M by > 8 (exp2 domain)
            if (!__all(pm - M_[g] <= 8.f)) {
                float nM = fmaxf(M_[g], pm);
                float scn = EXP2F(M_[g] - nM);
                L_[g] *= scn;
                #pragma unroll
                for (int i = 0; i < 4; ++i) {
                    float si = __shfl(scn, (lane & 48) + hi * 4 + i);
                    #pragma unroll
                    for (int f = 0; f < 8; ++f) acc[g][f][i] *= si;
                }
                M_[g] = nM;
            }
            float rs = 0.f;
            #pragma unroll
            for (int f = 0; f < 4; ++f)
                #pragma unroll
                for (int i = 0; i < 4; ++i) {
                    float e = EXP2F(sv[g][f][i] - M_[g]);
                    sv[g][f][i] = e;
                    rs += e;
                }
            rs += __shfl_xor(rs, 16);
            rs += __shfl_xor(rs, 32);
            L_[g] += rs;
            // P -> wave-private LDS as P[q][kv], packed b64 stores
            #pragma unroll
            for (int f = 0; f < 4; ++f) {
                bf16x4 p;
                p[0] = (bf16)sv[g][f][0]; p[1] = (bf16)sv[g][f][1];
                p[2] = (bf16)sv[g][f][2]; p[3] = (bf16)sv[g][f][3];
                *(bf16x4*)&Ps[wv][g * 16 + lo][f * 16 + hi * 4] = p;
            }
        }
        // O += P V
        __builtin_amdgcn_s_setprio(1);
        #pragma unroll
        for (int kk = 0; kk < 2; ++kk) {
            bf16x8 pa0 = *(const bf16x8*)&Ps[wv][lo][kk * 32 + hi * 8];
            bf16x8 pa1 = *(const bf16x8*)&Ps[wv][16 + lo][kk * 32 + hi * 8];
            #pragma unroll
            for (int f = 0; f < 8; ++f) {
                int row = f * 16 + lo;
                bf16x8 vf = *(const bf16x8*)&Vt[row][(kk * 32 + hi * 8) ^ ((row & 7) << 3)];
                acc[0][f] = MFMA16(pa0, vf, acc[0][f]);
                acc[1][f] = MFMA16(pa1, vf, acc[1][f]);
            }
        }
        __builtin_amdgcn_s_setprio(0);
    }
#undef ISSUE
    // write unnormalized partials (M in log2 domain)
    const size_t pb = ((size_t)b * CH + slot) * QB;
    #pragma unroll
    for (int g = 0; g < 2; ++g)
        #pragma unroll
        for (int f = 0; f < 8; ++f)
            #pragma unroll
            for (int i = 0; i < 4; ++i) {
                int row = wv * 32 + g * 16 + hi * 4 + i;
                Opart[(pb + row) * 128 + f * 16 + lo] = acc[g][f][i];
            }
    if (hi == 0) {
        #pragma unroll
        for (int g = 0; g < 2; ++g) {
            Mpart[pb + wv * 32 + g * 16 + lo] = M_[g];
            Lpart[pb + wv * 32 + g * 16 + lo] = L_[g];
        }
    }
}

// ---------------------------------------------------------------------------
// Kernel 3: combine chunk partials (exp2 domain). grid (NQB, B), block 256.
// ---------------------------------------------------------------------------
__global__ __launch_bounds__(256) void reduce_kernel(
    const float* __restrict__ Opart, const float* __restrict__ Mpart,
    const float* __restrict__ Lpart, float* __restrict__ out, int DIV, int CH)
{
    __shared__ float wexp[8][128];
    __shared__ float invL[128];
    const int qb = blockIdx.x, b = blockIdx.y, t = threadIdx.x;
    int pbase = 0, nact = 1;
    for (int j = 0; j <= qb; ++j) {
        int n = (2 * j + 2 + DIV - 1) / DIV;
        if (j == qb) { nact = n; break; }
        pbase += n;
    }
    const size_t pb = ((size_t)b * CH + pbase) * QB;
    if (t < 128) {
        float Mstar = -INFINITY;
        for (int c = 0; c < nact; ++c) Mstar = fmaxf(Mstar, Mpart[pb + c * QB + t]);
        float Ls = 0.f;
        for (int c = 0; c < nact; ++c) {
            float wc = __builtin_amdgcn_exp2f(Mpart[pb + c * QB + t] - Mstar);
            wexp[c][t] = wc;
            Ls += wc * Lpart[pb + c * QB + t];
        }
        invL[t] = 1.f / Ls;
    }
    __syncthreads();
    #pragma unroll
    for (int rep = 0; rep < 16; ++rep) {
        int idx = rep * 256 + t;
        int row = idx >> 5, c4 = (idx & 31) * 4;
        float ox = 0.f, oy = 0.f, oz = 0.f, ow = 0.f;
        for (int c = 0; c < nact; ++c) {
            float wc = wexp[c][row];
            float4 v = *(const float4*)(Opart + (pb + (size_t)c * QB + row) * 128 + c4);
            ox += wc * v.x; oy += wc * v.y; oz += wc * v.z; ow += wc * v.w;
        }
        float il = invL[row];
        float4 o = make_float4(ox * il, oy * il, oz * il, ow * il);
        *(float4*)(out + ((size_t)b * Ss + qb * QB + row) * 128 + c4) = o;
    }
}

extern "C" void kernel_launch(void* const* d_in, const int* in_sizes, int n_in,
                              void* d_out, int out_size, void* d_ws, size_t ws_size,
                              hipStream_t stream) {
    (void)in_sizes; (void)n_in; (void)out_size;
    const float* embds = (const float*)d_in[0];
    const float* Wq = (const float*)d_in[1];
    const float* bq = (const float*)d_in[2];
    const float* Wk = (const float*)d_in[3];
    const float* bk = (const float*)d_in[4];
    const float* Wv = (const float*)d_in[5];
    const float* bv = (const float*)d_in[6];

    char* ws = (char*)d_ws;
    size_t off = 0;
    bf16* Qb    = (bf16*)(ws + off); off += (size_t)Mrows * Hh * 2;
    bf16* Kb    = (bf16*)(ws + off); off += (size_t)Mrows * Hh * 2;
    bf16* Vtg   = (bf16*)(ws + off); off += (size_t)Mrows * Hh * 2;
    bf16* Wfrag = (bf16*)(ws + off); off += (size_t)3 * Hh * Ee * 2;

    auto chunks_for = [](int div) {
        int s = 0;
        for (int qb = 0; qb < NQB; ++qb) s += (2 * qb + 2 + div - 1) / div;
        return s;
    };
    auto need = [&](int ch) {
        return off + (size_t)Bb * ch * QB * 128 * 4 + (size_t)Bb * ch * QB * 8;
    };
    int DIV = 8;
    int CH = chunks_for(DIV);                     // 144
    if (need(CH) > ws_size) { DIV = 10; CH = chunks_for(DIV); }   // 119
    if (need(CH) > ws_size) { DIV = 20; CH = chunks_for(DIV); }   // 68
    float* Opart = (float*)(ws + off);
    size_t osz = (size_t)Bb * CH * QB * 128 * 4;
    float* Mp = (float*)(ws + off + osz);
    float* Lp = Mp + (size_t)Bb * CH * QB;

    wfrag_kernel<<<dim3(24), 256, 0, stream>>>(Wq, Wk, Wv, Wfrag);
    proj_kernel<<<dim3(Mrows / 32), 512, 0, stream>>>(embds, Wfrag, bq, bk, bv, Qb, Kb, Vtg);
    attn_kernel<<<dim3(CH, Bb), 256, 0, stream>>>(Qb, Kb, Vtg, Opart, Mp, Lp, DIV, CH);
    reduce_kernel<<<dim3(NQB, Bb), 256, 0, stream>>>(Opart, Mp, Lp, (float*)d_out, DIV, CH);
}

// Round 15
// 106.433 us; speedup vs baseline: 1.0746x; 1.0746x over previous
//
#include <hip/hip_runtime.h>

typedef __bf16 bf16;
typedef __attribute__((ext_vector_type(4))) bf16 bf16x4;
typedef __attribute__((ext_vector_type(8))) bf16 bf16x8;
typedef __attribute__((ext_vector_type(4))) float f32x4;

#define MFMA16(a, b, c) __builtin_amdgcn_mfma_f32_16x16x32_bf16(a, b, c, 0, 0, 0)
#define EXP2F(x) __builtin_amdgcn_exp2f(x)

constexpr int Bb = 4, Ss = 4096, Ee = 1024, Hh = 128;
constexpr int Mrows = Bb * Ss;  // 16384
constexpr int QB = 128;         // attn q-block
constexpr int NQB = Ss / QB;    // 32

// ---------------------------------------------------------------------------
// Kernel 0: build fragment-major Wfrag DIRECTLY from W (no Wt intermediate).
// Wfrag[((S*32 + ks)*64 + lane)*8 + j] = W_{S>>3}[ks*32 + (lane>>4)*8 + j]
//                                          [(S&7)*16 + (lane&15)]
// grid 24 (=S), block 256.
// ---------------------------------------------------------------------------
__global__ __launch_bounds__(256) void wfrag_kernel(
    const float* __restrict__ Wq, const float* __restrict__ Wk,
    const float* __restrict__ Wv, bf16* __restrict__ Wfrag)
{
    __shared__ bf16 Sb[1024][18];   // [k][col], padded row = 36B (2-way free)
    const int S = blockIdx.x, t = threadIdx.x;
    const float* W = ((S >> 3) == 0) ? Wq : ((S >> 3) == 1) ? Wk : Wv;
    const int c0 = (S & 7) * 16;
    #pragma unroll
    for (int j = 0; j < 4; ++j) {
        int k = t + 256 * j;
        const float4* src = (const float4*)(W + (size_t)k * Hh + c0);
        #pragma unroll
        for (int q = 0; q < 4; ++q) {
            float4 v = src[q];
            bf16x4 o; o[0] = (bf16)v.x; o[1] = (bf16)v.y; o[2] = (bf16)v.z; o[3] = (bf16)v.w;
            *(bf16x4*)&Sb[k][q * 4] = o;
        }
    }
    __syncthreads();
    const int lane = t & 63;
    #pragma unroll
    for (int r = 0; r < 8; ++r) {
        int ks = (t >> 6) + 4 * r;
        int kb = ks * 32 + (lane >> 4) * 8;
        bf16x8 o;
        #pragma unroll
        for (int j = 0; j < 8; ++j) o[j] = Sb[kb + j][lane & 15];
        *(bf16x8*)&Wfrag[(((size_t)S * 32 + ks) * 64 + lane) * 8] = o;
    }
}

// ---------------------------------------------------------------------------
// Kernel 1: fused QKV projection — A-resident bf16 panel + fragment-major B.
// grid (Mrows/32) = 512, block 512 (8 waves). Phase 1: stage 32x1024 embds
// f32 -> bf16 into chunk-XOR-swizzled LDS (one barrier). Phase 2: 32-step
// k-loop, ZERO barriers. Wave wv owns col-frags F = 3wv..3wv+2.
// V written transposed: Vtg[b][h][s]. Q pre-scaled by log2(e)/sqrt(H).
// ---------------------------------------------------------------------------
__global__ __launch_bounds__(512, 4) void proj_kernel(
    const float* __restrict__ embds, const bf16* __restrict__ Wfrag,
    const float* __restrict__ bq, const float* __restrict__ bk,
    const float* __restrict__ bv,
    bf16* __restrict__ Qb, bf16* __restrict__ Kb, bf16* __restrict__ Vtg)
{
    __shared__ bf16 As[32][1024];   // 64 KB; 16B chunk c stored at c^(row&15)

    const int t = threadIdx.x;
    const int wv = t >> 6, lane = t & 63, lo = lane & 15, hi = lane >> 4;
    const int m0 = blockIdx.x * 32;

    {
        const int row = t >> 4, cbc = (t & 15) * 8;
        const float4* src = (const float4*)(embds + (size_t)(m0 + row) * Ee + (t & 15) * 64);
        #pragma unroll
        for (int jj = 0; jj < 8; ++jj) {
            float4 v0 = src[2 * jj], v1 = src[2 * jj + 1];
            bf16x8 o;
            o[0] = (bf16)v0.x; o[1] = (bf16)v0.y; o[2] = (bf16)v0.z; o[3] = (bf16)v0.w;
            o[4] = (bf16)v1.x; o[5] = (bf16)v1.y; o[6] = (bf16)v1.z; o[7] = (bf16)v1.w;
            *(bf16x8*)&As[row][((cbc + jj) ^ (row & 15)) * 8] = o;
        }
    }
    __syncthreads();

    f32x4 acc[2][3];
    #pragma unroll
    for (int rg = 0; rg < 2; ++rg)
        #pragma unroll
        for (int f = 0; f < 3; ++f) acc[rg][f] = f32x4{0.f, 0.f, 0.f, 0.f};

    const bf16* bp0 = Wfrag + ((size_t)(wv * 3 + 0) * 32) * 512 + lane * 8;
    const bf16* bp1 = Wfrag + ((size_t)(wv * 3 + 1) * 32) * 512 + lane * 8;
    const bf16* bp2 = Wfrag + ((size_t)(wv * 3 + 2) * 32) * 512 + lane * 8;

    bf16x8 c0 = *(const bf16x8*)(bp0);
    bf16x8 c1 = *(const bf16x8*)(bp1);
    bf16x8 c2 = *(const bf16x8*)(bp2);
    bf16x8 n0 = *(const bf16x8*)(bp0 + 512);
    bf16x8 n1 = *(const bf16x8*)(bp1 + 512);
    bf16x8 n2 = *(const bf16x8*)(bp2 + 512);

    #pragma unroll
    for (int ks = 0; ks < 32; ++ks) {
        const int pos = ((ks * 4 + hi) ^ lo) * 8;
        bf16x8 a0 = *(const bf16x8*)&As[lo][pos];
        bf16x8 a1 = *(const bf16x8*)&As[16 + lo][pos];
        acc[0][0] = MFMA16(a0, c0, acc[0][0]);
        acc[1][0] = MFMA16(a1, c0, acc[1][0]);
        acc[0][1] = MFMA16(a0, c1, acc[0][1]);
        acc[1][1] = MFMA16(a1, c1, acc[1][1]);
        acc[0][2] = MFMA16(a0, c2, acc[0][2]);
        acc[1][2] = MFMA16(a1, c2, acc[1][2]);
        c0 = n0; c1 = n1; c2 = n2;
        if (ks + 2 < 32) {
            n0 = *(const bf16x8*)(bp0 + (ks + 2) * 512);
            n1 = *(const bf16x8*)(bp1 + (ks + 2) * 512);
            n2 = *(const bf16x8*)(bp2 + (ks + 2) * 512);
        }
    }

    #pragma unroll
    for (int f = 0; f < 3; ++f) {
        const int F = wv * 3 + f;
        const int p = F >> 3;
        const int col = (F & 7) * 16 + lo;
        const float* bias = (p == 0) ? bq : (p == 1) ? bk : bv;
        float bvv = bias[col];
        if (p == 2) {
            const int mb = m0 >> 12, s0l = m0 & 4095;
            #pragma unroll
            for (int rg = 0; rg < 2; ++rg)
                #pragma unroll
                for (int i = 0; i < 4; ++i) {
                    int s = s0l + rg * 16 + hi * 4 + i;
                    Vtg[((size_t)mb * Hh + col) * Ss + s] = (bf16)(acc[rg][f][i] + bvv);
                }
        } else {
            bf16* dst = (p == 0) ? Qb : Kb;
            // Q scale = log2(e)/sqrt(128): softmax runs in exp2 domain
            const float scale = (p == 0) ? 0.1275174407017663f : 1.0f;
            #pragma unroll
            for (int rg = 0; rg < 2; ++rg)
                #pragma unroll
                for (int i = 0; i < 4; ++i) {
                    int row = m0 + rg * 16 + hi * 4 + i;
                    dst[(size_t)row * Hh + col] = (bf16)((acc[rg][f][i] + bvv) * scale);
                }
        }
    }
}

// ---------------------------------------------------------------------------
// Kernel 2: split-KV causal flash attention, swapped QK^T, QBLK=128,
// exp2-domain softmax + defer-max (THR=8) + packed P stores + bf16 partials.
// grid (CH, B); block u covers qb with nchunks(qb) = ceil((2qb+2)/DIV).
// block 256 (4 waves x 32 q-rows, 2 q-groups).
// ---------------------------------------------------------------------------
__global__ __launch_bounds__(256, 2) void attn_kernel(
    const bf16* __restrict__ Qb, const bf16* __restrict__ Kb,
    const bf16* __restrict__ Vtg,
    bf16* __restrict__ Opart, float* __restrict__ Mpart, float* __restrict__ Lpart,
    int DIV, int CH)
{
    __shared__ bf16 Ks[64][136];   // K tile, stride 272B
    __shared__ bf16 Vt[128][64];   // V^T tile, (h&7)-XOR swizzled 16B chunks
    __shared__ bf16 Ps[4][32][72]; // wave-private P[q][kv], 2 q-groups

    const int t = threadIdx.x;
    const int wv = t >> 6, lane = t & 63, lo = lane & 15, hi = lane >> 4;
    const int slot = blockIdx.x, b = blockIdx.y;

    int u = slot, qb = 0, nch = 1;
    for (qb = 0; qb < NQB; ++qb) {
        nch = (2 * qb + 2 + DIV - 1) / DIV;
        if (u < nch) break;
        u -= nch;
    }
    const int ntiles = 2 * qb + 2;
    const int t0 = (u * ntiles) / nch;
    const int t1 = ((u + 1) * ntiles) / nch;

    const int q0 = qb * QB;
    const size_t base = (size_t)b * Ss * Hh;
    const size_t vbase = (size_t)b * Hh * Ss;

    const bf16* kg = Kb + base + (size_t)(t >> 4) * Hh + (t & 15) * 8;
    const bf16* vg = Vtg + vbase + (size_t)(t >> 3) * Ss + (t & 7) * 8;
    bf16* ksl = &Ks[t >> 4][(t & 15) * 8];
    bf16* vsl = &Vt[t >> 3][((t & 7) * 8) ^ (((t >> 3) & 7) << 3)];

    bf16x8 qf[2][4];
    #pragma unroll
    for (int g = 0; g < 2; ++g)
        #pragma unroll
        for (int kk = 0; kk < 4; ++kk)
            qf[g][kk] = *(const bf16x8*)(
                Qb + base + (size_t)(q0 + wv * 32 + g * 16 + lo) * Hh + kk * 32 + hi * 8);

    f32x4 acc[2][8];
    #pragma unroll
    for (int g = 0; g < 2; ++g)
        #pragma unroll
        for (int f = 0; f < 8; ++f) acc[g][f] = f32x4{0.f, 0.f, 0.f, 0.f};
    float M_[2] = {-1e30f, -1e30f};   // finite: fully-masked tiles stay NaN-free
    float L_[2] = {0.f, 0.f};

    uint4 kr0, kr1, kr2, kr3, vr0, vr1, vr2, vr3;
#define ISSUE(T) do {                                            \
        const bf16* kp_ = kg + (size_t)(T) * (64 * Hh);          \
        kr0 = *(const uint4*)(kp_);                              \
        kr1 = *(const uint4*)(kp_ + 16 * Hh);                    \
        kr2 = *(const uint4*)(kp_ + 32 * Hh);                    \
        kr3 = *(const uint4*)(kp_ + 48 * Hh);                    \
        const bf16* vp_ = vg + (T) * 64;                         \
        vr0 = *(const uint4*)(vp_);                              \
        vr1 = *(const uint4*)(vp_ + 32 * Ss);                    \
        vr2 = *(const uint4*)(vp_ + 64 * Ss);                    \
        vr3 = *(const uint4*)(vp_ + 96 * Ss);                    \
    } while (0)

    ISSUE(t0);
    for (int tile = t0; tile < t1; ++tile) {
        __syncthreads();   // previous tile's LDS reads done
        *(uint4*)(ksl) = kr0;
        *(uint4*)(ksl + 16 * 136) = kr1;
        *(uint4*)(ksl + 32 * 136) = kr2;
        *(uint4*)(ksl + 48 * 136) = kr3;
        *(uint4*)(vsl) = vr0;
        *(uint4*)(vsl + 32 * 64) = vr1;
        *(uint4*)(vsl + 64 * 64) = vr2;
        *(uint4*)(vsl + 96 * 64) = vr3;
        if (tile + 1 < t1) ISSUE(tile + 1);
        __syncthreads();
        const int kv0 = tile * 64;

        // S^T = K Q^T per q-group: D[kv][q], kv = f*16+hi*4+i, q = lo
        f32x4 sv[2][4];
        #pragma unroll
        for (int g = 0; g < 2; ++g)
            #pragma unroll
            for (int f = 0; f < 4; ++f) sv[g][f] = f32x4{0.f, 0.f, 0.f, 0.f};
        __builtin_amdgcn_s_setprio(1);
        #pragma unroll
        for (int kk = 0; kk < 4; ++kk) {
            #pragma unroll
            for (int f = 0; f < 4; ++f) {
                bf16x8 kf = *(const bf16x8*)&Ks[f * 16 + lo][kk * 32 + hi * 8];
                sv[0][f] = MFMA16(kf, qf[0][kk], sv[0][f]);
                sv[1][f] = MFMA16(kf, qf[1][kk], sv[1][f]);
            }
        }
        __builtin_amdgcn_s_setprio(0);

        #pragma unroll
        for (int g = 0; g < 2; ++g) {
            const int qg0 = q0 + wv * 32 + g * 16;   // wave-uniform per g
            if (kv0 + 63 > qg0) {                    // masking needed
                int qg = qg0 + lo;
                #pragma unroll
                for (int f = 0; f < 4; ++f)
                    #pragma unroll
                    for (int i = 0; i < 4; ++i)
                        if (kv0 + f * 16 + hi * 4 + i > qg) sv[g][f][i] = -INFINITY;
            }
            // row max (lane owns 16 kv of row q=lo): in-lane tree + 2 shuffles
            float pm = -INFINITY;
            #pragma unroll
            for (int f = 0; f < 4; ++f)
                pm = fmaxf(pm, fmaxf(fmaxf(sv[g][f][0], sv[g][f][1]),
                                     fmaxf(sv[g][f][2], sv[g][f][3])));
            pm = fmaxf(pm, __shfl_xor(pm, 16));
            pm = fmaxf(pm, __shfl_xor(pm, 32));
            // defer-max: rescale only when pm exceeds M by > 8 (exp2 domain)
            if (!__all(pm - M_[g] <= 8.f)) {
                float nM = fmaxf(M_[g], pm);
                float scn = EXP2F(M_[g] - nM);
                L_[g] *= scn;
                #pragma unroll
                for (int i = 0; i < 4; ++i) {
                    float si = __shfl(scn, (lane & 48) + hi * 4 + i);
                    #pragma unroll
                    for (int f = 0; f < 8; ++f) acc[g][f][i] *= si;
                }
                M_[g] = nM;
            }
            float rs = 0.f;
            #pragma unroll
            for (int f = 0; f < 4; ++f)
                #pragma unroll
                for (int i = 0; i < 4; ++i) {
                    float e = EXP2F(sv[g][f][i] - M_[g]);
                    sv[g][f][i] = e;
                    rs += e;
                }
            rs += __shfl_xor(rs, 16);
            rs += __shfl_xor(rs, 32);
            L_[g] += rs;
            // P -> wave-private LDS as P[q][kv], packed b64 stores
            #pragma unroll
            for (int f = 0; f < 4; ++f) {
                bf16x4 p;
                p[0] = (bf16)sv[g][f][0]; p[1] = (bf16)sv[g][f][1];
                p[2] = (bf16)sv[g][f][2]; p[3] = (bf16)sv[g][f][3];
                *(bf16x4*)&Ps[wv][g * 16 + lo][f * 16 + hi * 4] = p;
            }
        }
        // O += P V
        __builtin_amdgcn_s_setprio(1);
        #pragma unroll
        for (int kk = 0; kk < 2; ++kk) {
            bf16x8 pa0 = *(const bf16x8*)&Ps[wv][lo][kk * 32 + hi * 8];
            bf16x8 pa1 = *(const bf16x8*)&Ps[wv][16 + lo][kk * 32 + hi * 8];
            #pragma unroll
            for (int f = 0; f < 8; ++f) {
                int row = f * 16 + lo;
                bf16x8 vf = *(const bf16x8*)&Vt[row][(kk * 32 + hi * 8) ^ ((row & 7) << 3)];
                acc[0][f] = MFMA16(pa0, vf, acc[0][f]);
                acc[1][f] = MFMA16(pa1, vf, acc[1][f]);
            }
        }
        __builtin_amdgcn_s_setprio(0);
    }
#undef ISSUE
    // write unnormalized partials as bf16 (M in log2 domain, f32)
    const size_t pb = ((size_t)b * CH + slot) * QB;
    #pragma unroll
    for (int g = 0; g < 2; ++g)
        #pragma unroll
        for (int f = 0; f < 8; ++f)
            #pragma unroll
            for (int i = 0; i < 4; ++i) {
                int row = wv * 32 + g * 16 + hi * 4 + i;
                Opart[(pb + row) * 128 + f * 16 + lo] = (bf16)acc[g][f][i];
            }
    if (hi == 0) {
        #pragma unroll
        for (int g = 0; g < 2; ++g) {
            Mpart[pb + wv * 32 + g * 16 + lo] = M_[g];
            Lpart[pb + wv * 32 + g * 16 + lo] = L_[g];
        }
    }
}

// ---------------------------------------------------------------------------
// Kernel 3: combine chunk partials (exp2 domain, bf16 partials).
// grid (NQB, B), block 256.
// ---------------------------------------------------------------------------
__global__ __launch_bounds__(256) void reduce_kernel(
    const bf16* __restrict__ Opart, const float* __restrict__ Mpart,
    const float* __restrict__ Lpart, float* __restrict__ out, int DIV, int CH)
{
    __shared__ float wexp[8][128];
    __shared__ float invL[128];
    const int qb = blockIdx.x, b = blockIdx.y, t = threadIdx.x;
    int pbase = 0, nact = 1;
    for (int j = 0; j <= qb; ++j) {
        int n = (2 * j + 2 + DIV - 1) / DIV;
        if (j == qb) { nact = n; break; }
        pbase += n;
    }
    const size_t pb = ((size_t)b * CH + pbase) * QB;
    if (t < 128) {
        float Mstar = -INFINITY;
        for (int c = 0; c < nact; ++c) Mstar = fmaxf(Mstar, Mpart[pb + c * QB + t]);
        float Ls = 0.f;
        for (int c = 0; c < nact; ++c) {
            float wc = __builtin_amdgcn_exp2f(Mpart[pb + c * QB + t] - Mstar);
            wexp[c][t] = wc;
            Ls += wc * Lpart[pb + c * QB + t];
        }
        invL[t] = 1.f / Ls;
    }
    __syncthreads();
    #pragma unroll
    for (int rep = 0; rep < 16; ++rep) {
        int idx = rep * 256 + t;
        int row = idx >> 5, c4 = (idx & 31) * 4;
        float ox = 0.f, oy = 0.f, oz = 0.f, ow = 0.f;
        for (int c = 0; c < nact; ++c) {
            float wc = wexp[c][row];
            bf16x4 v = *(const bf16x4*)(Opart + (pb + (size_t)c * QB + row) * 128 + c4);
            ox += wc * (float)v[0]; oy += wc * (float)v[1];
            oz += wc * (float)v[2]; ow += wc * (float)v[3];
        }
        float il = invL[row];
        float4 o = make_float4(ox * il, oy * il, oz * il, ow * il);
        *(float4*)(out + ((size_t)b * Ss + qb * QB + row) * 128 + c4) = o;
    }
}

extern "C" void kernel_launch(void* const* d_in, const int* in_sizes, int n_in,
                              void* d_out, int out_size, void* d_ws, size_t ws_size,
                              hipStream_t stream) {
    (void)in_sizes; (void)n_in; (void)out_size;
    const float* embds = (const float*)d_in[0];
    const float* Wq = (const float*)d_in[1];
    const float* bq = (const float*)d_in[2];
    const float* Wk = (const float*)d_in[3];
    const float* bk = (const float*)d_in[4];
    const float* Wv = (const float*)d_in[5];
    const float* bv = (const float*)d_in[6];

    char* ws = (char*)d_ws;
    size_t off = 0;
    bf16* Qb    = (bf16*)(ws + off); off += (size_t)Mrows * Hh * 2;
    bf16* Kb    = (bf16*)(ws + off); off += (size_t)Mrows * Hh * 2;
    bf16* Vtg   = (bf16*)(ws + off); off += (size_t)Mrows * Hh * 2;
    bf16* Wfrag = (bf16*)(ws + off); off += (size_t)3 * Hh * Ee * 2;

    auto chunks_for = [](int div) {
        int s = 0;
        for (int qb = 0; qb < NQB; ++qb) s += (2 * qb + 2 + div - 1) / div;
        return s;
    };
    auto need = [&](int ch) {
        return off + (size_t)Bb * ch * QB * 128 * 2 + (size_t)Bb * ch * QB * 8;
    };
    int DIV = 10;
    int CH = chunks_for(DIV);                     // 119
    if (need(CH) > ws_size) { DIV = 20; CH = chunks_for(DIV); }   // 68
    bf16* Opart = (bf16*)(ws + off);
    size_t osz = (size_t)Bb * CH * QB * 128 * 2;
    float* Mp = (float*)(ws + off + osz);
    float* Lp = Mp + (size_t)Bb * CH * QB;

    wfrag_kernel<<<dim3(24), 256, 0, stream>>>(Wq, Wk, Wv, Wfrag);
    proj_kernel<<<dim3(Mrows / 32), 512, 0, stream>>>(embds, Wfrag, bq, bk, bv, Qb, Kb, Vtg);
    attn_kernel<<<dim3(CH, Bb), 256, 0, stream>>>(Qb, Kb, Vtg, Opart, Mp, Lp, DIV, CH);
    reduce_kernel<<<dim3(NQB, Bb), 256, 0, stream>>>(Opart, Mp, Lp, (float*)d_out, DIV, CH);
}

// Round 16
// 104.542 us; speedup vs baseline: 1.0940x; 1.0181x over previous
//
#include <hip/hip_runtime.h>

typedef __bf16 bf16;
typedef __attribute__((ext_vector_type(4))) bf16 bf16x4;
typedef __attribute__((ext_vector_type(8))) bf16 bf16x8;
typedef __attribute__((ext_vector_type(4))) float f32x4;

#define MFMA16(a, b, c) __builtin_amdgcn_mfma_f32_16x16x32_bf16(a, b, c, 0, 0, 0)
#define EXP2F(x) __builtin_amdgcn_exp2f(x)

constexpr int Bb = 4, Ss = 4096, Ee = 1024, Hh = 128;
constexpr int Mrows = Bb * Ss;  // 16384
constexpr int QB = 256;         // attn q-block (8 waves x 32 rows)
constexpr int NQB = Ss / QB;    // 16

// ---------------------------------------------------------------------------
// Kernel 0: build fragment-major Wfrag DIRECTLY from W.
// Wfrag[((S*32 + ks)*64 + lane)*8 + j] = W_{S>>3}[ks*32 + (lane>>4)*8 + j]
//                                          [(S&7)*16 + (lane&15)]
// grid 24 (=S), block 256.
// ---------------------------------------------------------------------------
__global__ __launch_bounds__(256) void wfrag_kernel(
    const float* __restrict__ Wq, const float* __restrict__ Wk,
    const float* __restrict__ Wv, bf16* __restrict__ Wfrag)
{
    __shared__ bf16 Sb[1024][18];   // [k][col], padded row = 36B
    const int S = blockIdx.x, t = threadIdx.x;
    const float* W = ((S >> 3) == 0) ? Wq : ((S >> 3) == 1) ? Wk : Wv;
    const int c0 = (S & 7) * 16;
    #pragma unroll
    for (int j = 0; j < 4; ++j) {
        int k = t + 256 * j;
        const float4* src = (const float4*)(W + (size_t)k * Hh + c0);
        #pragma unroll
        for (int q = 0; q < 4; ++q) {
            float4 v = src[q];
            bf16x4 o; o[0] = (bf16)v.x; o[1] = (bf16)v.y; o[2] = (bf16)v.z; o[3] = (bf16)v.w;
            *(bf16x4*)&Sb[k][q * 4] = o;
        }
    }
    __syncthreads();
    const int lane = t & 63;
    #pragma unroll
    for (int r = 0; r < 8; ++r) {
        int ks = (t >> 6) + 4 * r;
        int kb = ks * 32 + (lane >> 4) * 8;
        bf16x8 o;
        #pragma unroll
        for (int j = 0; j < 8; ++j) o[j] = Sb[kb + j][lane & 15];
        *(bf16x8*)&Wfrag[(((size_t)S * 32 + ks) * 64 + lane) * 8] = o;
    }
}

// ---------------------------------------------------------------------------
// Kernel 1: fused QKV projection — A-resident bf16 panel + fragment-major B.
// grid (Mrows/32) = 512, block 512 (8 waves). Phase 1: BURST-load the
// 32x1024 embds panel (16 float4/thread hoisted into registers, one vmcnt
// window) then convert+write swizzled (one barrier). Phase 2: 32-step
// k-loop, ZERO barriers. Wave wv owns col-frags F = 3wv..3wv+2.
// V written transposed: Vtg[b][h][s]. Q pre-scaled by log2(e)/sqrt(H).
// ---------------------------------------------------------------------------
__global__ __launch_bounds__(512, 4) void proj_kernel(
    const float* __restrict__ embds, const bf16* __restrict__ Wfrag,
    const float* __restrict__ bq, const float* __restrict__ bk,
    const float* __restrict__ bv,
    bf16* __restrict__ Qb, bf16* __restrict__ Kb, bf16* __restrict__ Vtg)
{
    __shared__ bf16 As[32][1024];   // 64 KB; 16B chunk c stored at c^(row&15)

    const int t = threadIdx.x;
    const int wv = t >> 6, lane = t & 63, lo = lane & 15, hi = lane >> 4;
    const int m0 = blockIdx.x * 32;

    // ---- phase 1: burst-load A panel, then convert+write swizzled ----
    {
        const int row = t >> 4, cbc = (t & 15) * 8;
        const float4* src = (const float4*)(embds + (size_t)(m0 + row) * Ee + (t & 15) * 64);
        float4 v[16];
        #pragma unroll
        for (int jj = 0; jj < 16; ++jj) v[jj] = src[jj];
        #pragma unroll
        for (int jj = 0; jj < 8; ++jj) {
            bf16x8 o;
            o[0] = (bf16)v[2*jj].x; o[1] = (bf16)v[2*jj].y;
            o[2] = (bf16)v[2*jj].z; o[3] = (bf16)v[2*jj].w;
            o[4] = (bf16)v[2*jj+1].x; o[5] = (bf16)v[2*jj+1].y;
            o[6] = (bf16)v[2*jj+1].z; o[7] = (bf16)v[2*jj+1].w;
            *(bf16x8*)&As[row][((cbc + jj) ^ (row & 15)) * 8] = o;
        }
    }
    __syncthreads();

    // ---- phase 2: barrier-free k-loop ----
    f32x4 acc[2][3];
    #pragma unroll
    for (int rg = 0; rg < 2; ++rg)
        #pragma unroll
        for (int f = 0; f < 3; ++f) acc[rg][f] = f32x4{0.f, 0.f, 0.f, 0.f};

    const bf16* bp0 = Wfrag + ((size_t)(wv * 3 + 0) * 32) * 512 + lane * 8;
    const bf16* bp1 = Wfrag + ((size_t)(wv * 3 + 1) * 32) * 512 + lane * 8;
    const bf16* bp2 = Wfrag + ((size_t)(wv * 3 + 2) * 32) * 512 + lane * 8;

    bf16x8 c0 = *(const bf16x8*)(bp0);
    bf16x8 c1 = *(const bf16x8*)(bp1);
    bf16x8 c2 = *(const bf16x8*)(bp2);
    bf16x8 n0 = *(const bf16x8*)(bp0 + 512);
    bf16x8 n1 = *(const bf16x8*)(bp1 + 512);
    bf16x8 n2 = *(const bf16x8*)(bp2 + 512);

    #pragma unroll
    for (int ks = 0; ks < 32; ++ks) {
        const int pos = ((ks * 4 + hi) ^ lo) * 8;
        bf16x8 a0 = *(const bf16x8*)&As[lo][pos];
        bf16x8 a1 = *(const bf16x8*)&As[16 + lo][pos];
        acc[0][0] = MFMA16(a0, c0, acc[0][0]);
        acc[1][0] = MFMA16(a1, c0, acc[1][0]);
        acc[0][1] = MFMA16(a0, c1, acc[0][1]);
        acc[1][1] = MFMA16(a1, c1, acc[1][1]);
        acc[0][2] = MFMA16(a0, c2, acc[0][2]);
        acc[1][2] = MFMA16(a1, c2, acc[1][2]);
        c0 = n0; c1 = n1; c2 = n2;
        if (ks + 2 < 32) {
            n0 = *(const bf16x8*)(bp0 + (ks + 2) * 512);
            n1 = *(const bf16x8*)(bp1 + (ks + 2) * 512);
            n2 = *(const bf16x8*)(bp2 + (ks + 2) * 512);
        }
    }

    // ---- epilogue ----
    #pragma unroll
    for (int f = 0; f < 3; ++f) {
        const int F = wv * 3 + f;
        const int p = F >> 3;
        const int col = (F & 7) * 16 + lo;
        const float* bias = (p == 0) ? bq : (p == 1) ? bk : bv;
        float bvv = bias[col];
        if (p == 2) {
            const int mb = m0 >> 12, s0l = m0 & 4095;
            #pragma unroll
            for (int rg = 0; rg < 2; ++rg)
                #pragma unroll
                for (int i = 0; i < 4; ++i) {
                    int s = s0l + rg * 16 + hi * 4 + i;
                    Vtg[((size_t)mb * Hh + col) * Ss + s] = (bf16)(acc[rg][f][i] + bvv);
                }
        } else {
            bf16* dst = (p == 0) ? Qb : Kb;
            // Q scale = log2(e)/sqrt(128): softmax runs in exp2 domain
            const float scale = (p == 0) ? 0.1275174407017663f : 1.0f;
            #pragma unroll
            for (int rg = 0; rg < 2; ++rg)
                #pragma unroll
                for (int i = 0; i < 4; ++i) {
                    int row = m0 + rg * 16 + hi * 4 + i;
                    dst[(size_t)row * Hh + col] = (bf16)((acc[rg][f][i] + bvv) * scale);
                }
        }
    }
}

// ---------------------------------------------------------------------------
// Kernel 2: split-KV causal flash attention, swapped QK^T, QBLK=256
// (8 waves x 32 q-rows), exp2 softmax + defer-max + packed P + bf16 partials.
// grid (CH, B); block u covers qb with nchunks(qb) = ceil((4qb+4)/DIV).
// ---------------------------------------------------------------------------
__global__ __launch_bounds__(512, 2) void attn_kernel(
    const bf16* __restrict__ Qb, const bf16* __restrict__ Kb,
    const bf16* __restrict__ Vtg,
    bf16* __restrict__ Opart, float* __restrict__ Mpart, float* __restrict__ Lpart,
    int DIV, int CH)
{
    __shared__ bf16 Ks[64][136];   // K tile, stride 272B
    __shared__ bf16 Vt[128][64];   // V^T tile, (h&7)-XOR swizzled 16B chunks
    __shared__ bf16 Ps[8][32][72]; // wave-private P[q][kv]

    const int t = threadIdx.x;
    const int wv = t >> 6, lane = t & 63, lo = lane & 15, hi = lane >> 4;
    const int slot = blockIdx.x, b = blockIdx.y;

    int u = slot, qb = 0, nch = 1;
    for (qb = 0; qb < NQB; ++qb) {
        nch = (4 * qb + 4 + DIV - 1) / DIV;
        if (u < nch) break;
        u -= nch;
    }
    const int ntiles = 4 * qb + 4;
    const int t0 = (u * ntiles) / nch;
    const int t1 = ((u + 1) * ntiles) / nch;

    const int q0 = qb * QB;
    const size_t base = (size_t)b * Ss * Hh;
    const size_t vbase = (size_t)b * Hh * Ss;

    // staging: 512 threads, 2 uint4 each for K (rows t>>4, +32) and
    // V^T (h rows t>>3, +64; swizzle invariant under h+64)
    const bf16* kg = Kb + base + (size_t)(t >> 4) * Hh + (t & 15) * 8;
    const bf16* vg = Vtg + vbase + (size_t)(t >> 3) * Ss + (t & 7) * 8;
    bf16* ksl = &Ks[t >> 4][(t & 15) * 8];
    bf16* vsl = &Vt[t >> 3][((t & 7) * 8) ^ (((t >> 3) & 7) << 3)];

    bf16x8 qf[2][4];
    #pragma unroll
    for (int g = 0; g < 2; ++g)
        #pragma unroll
        for (int kk = 0; kk < 4; ++kk)
            qf[g][kk] = *(const bf16x8*)(
                Qb + base + (size_t)(q0 + wv * 32 + g * 16 + lo) * Hh + kk * 32 + hi * 8);

    f32x4 acc[2][8];
    #pragma unroll
    for (int g = 0; g < 2; ++g)
        #pragma unroll
        for (int f = 0; f < 8; ++f) acc[g][f] = f32x4{0.f, 0.f, 0.f, 0.f};
    float M_[2] = {-1e30f, -1e30f};
    float L_[2] = {0.f, 0.f};

    uint4 kr0, kr1, vr0, vr1;
#define ISSUE(T) do {                                            \
        const bf16* kp_ = kg + (size_t)(T) * (64 * Hh);          \
        kr0 = *(const uint4*)(kp_);                              \
        kr1 = *(const uint4*)(kp_ + 32 * Hh);                    \
        const bf16* vp_ = vg + (T) * 64;                         \
        vr0 = *(const uint4*)(vp_);                              \
        vr1 = *(const uint4*)(vp_ + 64 * Ss);                    \
    } while (0)

    ISSUE(t0);
    for (int tile = t0; tile < t1; ++tile) {
        __syncthreads();   // previous tile's LDS reads done
        *(uint4*)(ksl) = kr0;
        *(uint4*)(ksl + 32 * 136) = kr1;
        *(uint4*)(vsl) = vr0;
        *(uint4*)(vsl + 64 * 64) = vr1;
        if (tile + 1 < t1) ISSUE(tile + 1);
        __syncthreads();
        const int kv0 = tile * 64;

        // S^T = K Q^T per q-group: D[kv][q], kv = f*16+hi*4+i, q = lo
        f32x4 sv[2][4];
        #pragma unroll
        for (int g = 0; g < 2; ++g)
            #pragma unroll
            for (int f = 0; f < 4; ++f) sv[g][f] = f32x4{0.f, 0.f, 0.f, 0.f};
        __builtin_amdgcn_s_setprio(1);
        #pragma unroll
        for (int kk = 0; kk < 4; ++kk) {
            #pragma unroll
            for (int f = 0; f < 4; ++f) {
                bf16x8 kf = *(const bf16x8*)&Ks[f * 16 + lo][kk * 32 + hi * 8];
                sv[0][f] = MFMA16(kf, qf[0][kk], sv[0][f]);
                sv[1][f] = MFMA16(kf, qf[1][kk], sv[1][f]);
            }
        }
        __builtin_amdgcn_s_setprio(0);

        #pragma unroll
        for (int g = 0; g < 2; ++g) {
            const int qg0 = q0 + wv * 32 + g * 16;   // wave-uniform per g
            if (kv0 + 63 > qg0) {
                int qg = qg0 + lo;
                #pragma unroll
                for (int f = 0; f < 4; ++f)
                    #pragma unroll
                    for (int i = 0; i < 4; ++i)
                        if (kv0 + f * 16 + hi * 4 + i > qg) sv[g][f][i] = -INFINITY;
            }
            float pm = -INFINITY;
            #pragma unroll
            for (int f = 0; f < 4; ++f)
                pm = fmaxf(pm, fmaxf(fmaxf(sv[g][f][0], sv[g][f][1]),
                                     fmaxf(sv[g][f][2], sv[g][f][3])));
            pm = fmaxf(pm, __shfl_xor(pm, 16));
            pm = fmaxf(pm, __shfl_xor(pm, 32));
            if (!__all(pm - M_[g] <= 8.f)) {
                float nM = fmaxf(M_[g], pm);
                float scn = EXP2F(M_[g] - nM);
                L_[g] *= scn;
                #pragma unroll
                for (int i = 0; i < 4; ++i) {
                    float si = __shfl(scn, (lane & 48) + hi * 4 + i);
                    #pragma unroll
                    for (int f = 0; f < 8; ++f) acc[g][f][i] *= si;
                }
                M_[g] = nM;
            }
            float rs = 0.f;
            #pragma unroll
            for (int f = 0; f < 4; ++f)
                #pragma unroll
                for (int i = 0; i < 4; ++i) {
                    float e = EXP2F(sv[g][f][i] - M_[g]);
                    sv[g][f][i] = e;
                    rs += e;
                }
            rs += __shfl_xor(rs, 16);
            rs += __shfl_xor(rs, 32);
            L_[g] += rs;
            #pragma unroll
            for (int f = 0; f < 4; ++f) {
                bf16x4 p;
                p[0] = (bf16)sv[g][f][0]; p[1] = (bf16)sv[g][f][1];
                p[2] = (bf16)sv[g][f][2]; p[3] = (bf16)sv[g][f][3];
                *(bf16x4*)&Ps[wv][g * 16 + lo][f * 16 + hi * 4] = p;
            }
        }
        // O += P V
        __builtin_amdgcn_s_setprio(1);
        #pragma unroll
        for (int kk = 0; kk < 2; ++kk) {
            bf16x8 pa0 = *(const bf16x8*)&Ps[wv][lo][kk * 32 + hi * 8];
            bf16x8 pa1 = *(const bf16x8*)&Ps[wv][16 + lo][kk * 32 + hi * 8];
            #pragma unroll
            for (int f = 0; f < 8; ++f) {
                int row = f * 16 + lo;
                bf16x8 vf = *(const bf16x8*)&Vt[row][(kk * 32 + hi * 8) ^ ((row & 7) << 3)];
                acc[0][f] = MFMA16(pa0, vf, acc[0][f]);
                acc[1][f] = MFMA16(pa1, vf, acc[1][f]);
            }
        }
        __builtin_amdgcn_s_setprio(0);
    }
#undef ISSUE
    // write unnormalized partials as bf16 (M in log2 domain, f32)
    const size_t pb = ((size_t)b * CH + slot) * QB;
    #pragma unroll
    for (int g = 0; g < 2; ++g)
        #pragma unroll
        for (int f = 0; f < 8; ++f)
            #pragma unroll
            for (int i = 0; i < 4; ++i) {
                int row = wv * 32 + g * 16 + hi * 4 + i;
                Opart[(pb + row) * 128 + f * 16 + lo] = (bf16)acc[g][f][i];
            }
    if (hi == 0) {
        #pragma unroll
        for (int g = 0; g < 2; ++g) {
            Mpart[pb + wv * 32 + g * 16 + lo] = M_[g];
            Lpart[pb + wv * 32 + g * 16 + lo] = L_[g];
        }
    }
}

// ---------------------------------------------------------------------------
// Kernel 3: combine chunk partials (exp2 domain, bf16 partials).
// grid (NQB*2, B), block 256; each block handles a 128-row half of a q-block.
// ---------------------------------------------------------------------------
__global__ __launch_bounds__(256) void reduce_kernel(
    const bf16* __restrict__ Opart, const float* __restrict__ Mpart,
    const float* __restrict__ Lpart, float* __restrict__ out, int DIV, int CH)
{
    __shared__ float wexp[7][128];
    __shared__ float invL[128];
    const int qb = blockIdx.x >> 1, half = blockIdx.x & 1;
    const int b = blockIdx.y, t = threadIdx.x;
    const int r0 = half * 128;
    int pbase = 0, nact = 1;
    for (int j = 0; j <= qb; ++j) {
        int n = (4 * j + 4 + DIV - 1) / DIV;
        if (j == qb) { nact = n; break; }
        pbase += n;
    }
    const size_t pb = ((size_t)b * CH + pbase) * QB;
    if (t < 128) {
        float Mstar = -INFINITY;
        for (int c = 0; c < nact; ++c)
            Mstar = fmaxf(Mstar, Mpart[pb + c * QB + r0 + t]);
        float Ls = 0.f;
        for (int c = 0; c < nact; ++c) {
            float wc = __builtin_amdgcn_exp2f(Mpart[pb + c * QB + r0 + t] - Mstar);
            wexp[c][t] = wc;
            Ls += wc * Lpart[pb + c * QB + r0 + t];
        }
        invL[t] = 1.f / Ls;
    }
    __syncthreads();
    #pragma unroll
    for (int rep = 0; rep < 16; ++rep) {
        int idx = rep * 256 + t;
        int row = idx >> 5, c4 = (idx & 31) * 4;
        float ox = 0.f, oy = 0.f, oz = 0.f, ow = 0.f;
        for (int c = 0; c < nact; ++c) {
            float wc = wexp[c][row];
            bf16x4 v = *(const bf16x4*)(Opart + (pb + (size_t)c * QB + r0 + row) * 128 + c4);
            ox += wc * (float)v[0]; oy += wc * (float)v[1];
            oz += wc * (float)v[2]; ow += wc * (float)v[3];
        }
        float il = invL[row];
        float4 o = make_float4(ox * il, oy * il, oz * il, ow * il);
        *(float4*)(out + ((size_t)b * Ss + qb * QB + r0 + row) * 128 + c4) = o;
    }
}

extern "C" void kernel_launch(void* const* d_in, const int* in_sizes, int n_in,
                              void* d_out, int out_size, void* d_ws, size_t ws_size,
                              hipStream_t stream) {
    (void)in_sizes; (void)n_in; (void)out_size;
    const float* embds = (const float*)d_in[0];
    const float* Wq = (const float*)d_in[1];
    const float* bq = (const float*)d_in[2];
    const float* Wk = (const float*)d_in[3];
    const float* bk = (const float*)d_in[4];
    const float* Wv = (const float*)d_in[5];
    const float* bv = (const float*)d_in[6];

    char* ws = (char*)d_ws;
    size_t off = 0;
    bf16* Qb    = (bf16*)(ws + off); off += (size_t)Mrows * Hh * 2;
    bf16* Kb    = (bf16*)(ws + off); off += (size_t)Mrows * Hh * 2;
    bf16* Vtg   = (bf16*)(ws + off); off += (size_t)Mrows * Hh * 2;
    bf16* Wfrag = (bf16*)(ws + off); off += (size_t)3 * Hh * Ee * 2;

    auto chunks_for = [](int div) {
        int s = 0;
        for (int qb = 0; qb < NQB; ++qb) s += (4 * qb + 4 + div - 1) / div;
        return s;
    };
    auto need = [&](int ch) {
        return off + (size_t)Bb * ch * QB * 128 * 2 + (size_t)Bb * ch * QB * 8;
    };
    int DIV = 10;
    int CH = chunks_for(DIV);                     // 61
    if (need(CH) > ws_size) { DIV = 20; CH = chunks_for(DIV); }
    bf16* Opart = (bf16*)(ws + off);
    size_t osz = (size_t)Bb * CH * QB * 128 * 2;
    float* Mp = (float*)(ws + off + osz);
    float* Lp = Mp + (size_t)Bb * CH * QB;

    wfrag_kernel<<<dim3(24), 256, 0, stream>>>(Wq, Wk, Wv, Wfrag);
    proj_kernel<<<dim3(Mrows / 32), 512, 0, stream>>>(embds, Wfrag, bq, bk, bv, Qb, Kb, Vtg);
    attn_kernel<<<dim3(CH, Bb), 512, 0, stream>>>(Qb, Kb, Vtg, Opart, Mp, Lp, DIV, CH);
    reduce_kernel<<<dim3(NQB * 2, Bb), 256, 0, stream>>>(Opart, Mp, Lp, (float*)d_out, DIV, CH);
}

// Round 17
// 99.945 us; speedup vs baseline: 1.1443x; 1.0460x over previous
//
#include <hip/hip_runtime.h>

typedef __bf16 bf16;
typedef __attribute__((ext_vector_type(4))) bf16 bf16x4;
typedef __attribute__((ext_vector_type(8))) bf16 bf16x8;
typedef __attribute__((ext_vector_type(4))) float f32x4;

#define MFMA16(a, b, c) __builtin_amdgcn_mfma_f32_16x16x32_bf16(a, b, c, 0, 0, 0)
#define EXP2F(x) __builtin_amdgcn_exp2f(x)

constexpr int Bb = 4, Ss = 4096, Ee = 1024, Hh = 128;
constexpr int Mrows = Bb * Ss;  // 16384
constexpr int QB = 256;         // attn q-block (8 waves x 32 rows)
constexpr int NQB = Ss / QB;    // 16

// ---------------------------------------------------------------------------
// Kernel 0: build fragment-major Wfrag DIRECTLY from W.
// Wfrag[((S*32 + ks)*64 + lane)*8 + j] = W_{S>>3}[ks*32 + (lane>>4)*8 + j]
//                                          [(S&7)*16 + (lane&15)]
// grid 24 (=S), block 256.
// ---------------------------------------------------------------------------
__global__ __launch_bounds__(256) void wfrag_kernel(
    const float* __restrict__ Wq, const float* __restrict__ Wk,
    const float* __restrict__ Wv, bf16* __restrict__ Wfrag)
{
    __shared__ bf16 Sb[1024][18];   // [k][col], padded row = 36B
    const int S = blockIdx.x, t = threadIdx.x;
    const float* W = ((S >> 3) == 0) ? Wq : ((S >> 3) == 1) ? Wk : Wv;
    const int c0 = (S & 7) * 16;
    #pragma unroll
    for (int j = 0; j < 4; ++j) {
        int k = t + 256 * j;
        const float4* src = (const float4*)(W + (size_t)k * Hh + c0);
        #pragma unroll
        for (int q = 0; q < 4; ++q) {
            float4 v = src[q];
            bf16x4 o; o[0] = (bf16)v.x; o[1] = (bf16)v.y; o[2] = (bf16)v.z; o[3] = (bf16)v.w;
            *(bf16x4*)&Sb[k][q * 4] = o;
        }
    }
    __syncthreads();
    const int lane = t & 63;
    #pragma unroll
    for (int r = 0; r < 8; ++r) {
        int ks = (t >> 6) + 4 * r;
        int kb = ks * 32 + (lane >> 4) * 8;
        bf16x8 o;
        #pragma unroll
        for (int j = 0; j < 8; ++j) o[j] = Sb[kb + j][lane & 15];
        *(bf16x8*)&Wfrag[(((size_t)S * 32 + ks) * 64 + lane) * 8] = o;
    }
}

// ---------------------------------------------------------------------------
// Kernel 1: fused QKV projection — 64-row A-resident panel (128 KB LDS) +
// fragment-major B. grid (Mrows/64) = 256 (1 block/CU), block 512 (8 waves).
// Each B-load feeds 4 MFMA (row-groups) -> B L2 traffic halves vs 32-row.
// Phase 1: stage 64x1024 embds f32 -> bf16 swizzled (one barrier).
// Phase 2: 32-step k-loop, ZERO barriers: 4 ds_read_b128 A-frags + 3
// coalesced 1KB B loads (depth-2 reg prefetch) + 12 MFMA per step.
// Wave wv owns col-frags F = 3wv..3wv+2 (F>>3 = proj, (F&7)*16 = col).
// V written transposed: Vtg[b][h][s]. Q pre-scaled by log2(e)/sqrt(H).
// ---------------------------------------------------------------------------
__global__ __launch_bounds__(512) void proj_kernel(
    const float* __restrict__ embds, const bf16* __restrict__ Wfrag,
    const float* __restrict__ bq, const float* __restrict__ bk,
    const float* __restrict__ bv,
    bf16* __restrict__ Qb, bf16* __restrict__ Kb, bf16* __restrict__ Vtg)
{
    __shared__ bf16 As[64][1024];   // 128 KB; 16B chunk c stored at c^(row&15)

    const int t = threadIdx.x;
    const int wv = t >> 6, lane = t & 63, lo = lane & 15, hi = lane >> 4;
    const int m0 = blockIdx.x * 64;

    // ---- phase 1: A panel f32 -> bf16, swizzled (2 bursts of 16 float4) ----
    {
        const int row = t >> 3, cb = (t & 7) * 16;   // 16 chunks/thread
        const float4* src = (const float4*)(embds + (size_t)(m0 + row) * Ee + (t & 7) * 128);
        #pragma unroll
        for (int half = 0; half < 2; ++half) {
            float4 v[16];
            #pragma unroll
            for (int jj = 0; jj < 16; ++jj) v[jj] = src[half * 16 + jj];
            #pragma unroll
            for (int jj = 0; jj < 8; ++jj) {
                bf16x8 o;
                o[0] = (bf16)v[2*jj].x; o[1] = (bf16)v[2*jj].y;
                o[2] = (bf16)v[2*jj].z; o[3] = (bf16)v[2*jj].w;
                o[4] = (bf16)v[2*jj+1].x; o[5] = (bf16)v[2*jj+1].y;
                o[6] = (bf16)v[2*jj+1].z; o[7] = (bf16)v[2*jj+1].w;
                *(bf16x8*)&As[row][((cb + half * 8 + jj) ^ (row & 15)) * 8] = o;
            }
        }
    }
    __syncthreads();

    // ---- phase 2: barrier-free k-loop ----
    f32x4 acc[4][3];
    #pragma unroll
    for (int rg = 0; rg < 4; ++rg)
        #pragma unroll
        for (int f = 0; f < 3; ++f) acc[rg][f] = f32x4{0.f, 0.f, 0.f, 0.f};

    const bf16* bp0 = Wfrag + ((size_t)(wv * 3 + 0) * 32) * 512 + lane * 8;
    const bf16* bp1 = Wfrag + ((size_t)(wv * 3 + 1) * 32) * 512 + lane * 8;
    const bf16* bp2 = Wfrag + ((size_t)(wv * 3 + 2) * 32) * 512 + lane * 8;

    bf16x8 c0 = *(const bf16x8*)(bp0);
    bf16x8 c1 = *(const bf16x8*)(bp1);
    bf16x8 c2 = *(const bf16x8*)(bp2);
    bf16x8 n0 = *(const bf16x8*)(bp0 + 512);
    bf16x8 n1 = *(const bf16x8*)(bp1 + 512);
    bf16x8 n2 = *(const bf16x8*)(bp2 + 512);

    #pragma unroll
    for (int ks = 0; ks < 32; ++ks) {
        const int pos = ((ks * 4 + hi) ^ lo) * 8;
        bf16x8 a0 = *(const bf16x8*)&As[lo][pos];
        bf16x8 a1 = *(const bf16x8*)&As[16 + lo][pos];
        bf16x8 a2 = *(const bf16x8*)&As[32 + lo][pos];
        bf16x8 a3 = *(const bf16x8*)&As[48 + lo][pos];
        __builtin_amdgcn_s_setprio(1);
        acc[0][0] = MFMA16(a0, c0, acc[0][0]);
        acc[1][0] = MFMA16(a1, c0, acc[1][0]);
        acc[2][0] = MFMA16(a2, c0, acc[2][0]);
        acc[3][0] = MFMA16(a3, c0, acc[3][0]);
        acc[0][1] = MFMA16(a0, c1, acc[0][1]);
        acc[1][1] = MFMA16(a1, c1, acc[1][1]);
        acc[2][1] = MFMA16(a2, c1, acc[2][1]);
        acc[3][1] = MFMA16(a3, c1, acc[3][1]);
        acc[0][2] = MFMA16(a0, c2, acc[0][2]);
        acc[1][2] = MFMA16(a1, c2, acc[1][2]);
        acc[2][2] = MFMA16(a2, c2, acc[2][2]);
        acc[3][2] = MFMA16(a3, c2, acc[3][2]);
        __builtin_amdgcn_s_setprio(0);
        c0 = n0; c1 = n1; c2 = n2;
        if (ks + 2 < 32) {
            n0 = *(const bf16x8*)(bp0 + (ks + 2) * 512);
            n1 = *(const bf16x8*)(bp1 + (ks + 2) * 512);
            n2 = *(const bf16x8*)(bp2 + (ks + 2) * 512);
        }
    }

    // ---- epilogue: frag F -> proj/col; V transposed ----
    #pragma unroll
    for (int f = 0; f < 3; ++f) {
        const int F = wv * 3 + f;
        const int p = F >> 3;
        const int col = (F & 7) * 16 + lo;
        const float* bias = (p == 0) ? bq : (p == 1) ? bk : bv;
        float bvv = bias[col];
        if (p == 2) {
            const int mb = m0 >> 12, s0l = m0 & 4095;
            #pragma unroll
            for (int rg = 0; rg < 4; ++rg)
                #pragma unroll
                for (int i = 0; i < 4; ++i) {
                    int s = s0l + rg * 16 + hi * 4 + i;
                    Vtg[((size_t)mb * Hh + col) * Ss + s] = (bf16)(acc[rg][f][i] + bvv);
                }
        } else {
            bf16* dst = (p == 0) ? Qb : Kb;
            // Q scale = log2(e)/sqrt(128): softmax runs in exp2 domain
            const float scale = (p == 0) ? 0.1275174407017663f : 1.0f;
            #pragma unroll
            for (int rg = 0; rg < 4; ++rg)
                #pragma unroll
                for (int i = 0; i < 4; ++i) {
                    int row = m0 + rg * 16 + hi * 4 + i;
                    dst[(size_t)row * Hh + col] = (bf16)((acc[rg][f][i] + bvv) * scale);
                }
        }
    }
}

// ---------------------------------------------------------------------------
// Kernel 2: split-KV causal flash attention, swapped QK^T, QBLK=256
// (8 waves x 32 q-rows), exp2 softmax + defer-max + packed P + bf16 partials.
// grid (CH, B); block u covers qb with nchunks(qb) = ceil((4qb+4)/DIV).
// ---------------------------------------------------------------------------
__global__ __launch_bounds__(512, 2) void attn_kernel(
    const bf16* __restrict__ Qb, const bf16* __restrict__ Kb,
    const bf16* __restrict__ Vtg,
    bf16* __restrict__ Opart, float* __restrict__ Mpart, float* __restrict__ Lpart,
    int DIV, int CH)
{
    __shared__ bf16 Ks[64][136];   // K tile, stride 272B
    __shared__ bf16 Vt[128][64];   // V^T tile, (h&7)-XOR swizzled 16B chunks
    __shared__ bf16 Ps[8][32][72]; // wave-private P[q][kv]

    const int t = threadIdx.x;
    const int wv = t >> 6, lane = t & 63, lo = lane & 15, hi = lane >> 4;
    const int slot = blockIdx.x, b = blockIdx.y;

    int u = slot, qb = 0, nch = 1;
    for (qb = 0; qb < NQB; ++qb) {
        nch = (4 * qb + 4 + DIV - 1) / DIV;
        if (u < nch) break;
        u -= nch;
    }
    const int ntiles = 4 * qb + 4;
    const int t0 = (u * ntiles) / nch;
    const int t1 = ((u + 1) * ntiles) / nch;

    const int q0 = qb * QB;
    const size_t base = (size_t)b * Ss * Hh;
    const size_t vbase = (size_t)b * Hh * Ss;

    const bf16* kg = Kb + base + (size_t)(t >> 4) * Hh + (t & 15) * 8;
    const bf16* vg = Vtg + vbase + (size_t)(t >> 3) * Ss + (t & 7) * 8;
    bf16* ksl = &Ks[t >> 4][(t & 15) * 8];
    bf16* vsl = &Vt[t >> 3][((t & 7) * 8) ^ (((t >> 3) & 7) << 3)];

    bf16x8 qf[2][4];
    #pragma unroll
    for (int g = 0; g < 2; ++g)
        #pragma unroll
        for (int kk = 0; kk < 4; ++kk)
            qf[g][kk] = *(const bf16x8*)(
                Qb + base + (size_t)(q0 + wv * 32 + g * 16 + lo) * Hh + kk * 32 + hi * 8);

    f32x4 acc[2][8];
    #pragma unroll
    for (int g = 0; g < 2; ++g)
        #pragma unroll
        for (int f = 0; f < 8; ++f) acc[g][f] = f32x4{0.f, 0.f, 0.f, 0.f};
    float M_[2] = {-1e30f, -1e30f};
    float L_[2] = {0.f, 0.f};

    uint4 kr0, kr1, vr0, vr1;
#define ISSUE(T) do {                                            \
        const bf16* kp_ = kg + (size_t)(T) * (64 * Hh);          \
        kr0 = *(const uint4*)(kp_);                              \
        kr1 = *(const uint4*)(kp_ + 32 * Hh);                    \
        const bf16* vp_ = vg + (T) * 64;                         \
        vr0 = *(const uint4*)(vp_);                              \
        vr1 = *(const uint4*)(vp_ + 64 * Ss);                    \
    } while (0)

    ISSUE(t0);
    for (int tile = t0; tile < t1; ++tile) {
        __syncthreads();   // previous tile's LDS reads done
        *(uint4*)(ksl) = kr0;
        *(uint4*)(ksl + 32 * 136) = kr1;
        *(uint4*)(vsl) = vr0;
        *(uint4*)(vsl + 64 * 64) = vr1;
        if (tile + 1 < t1) ISSUE(tile + 1);
        __syncthreads();
        const int kv0 = tile * 64;

        f32x4 sv[2][4];
        #pragma unroll
        for (int g = 0; g < 2; ++g)
            #pragma unroll
            for (int f = 0; f < 4; ++f) sv[g][f] = f32x4{0.f, 0.f, 0.f, 0.f};
        __builtin_amdgcn_s_setprio(1);
        #pragma unroll
        for (int kk = 0; kk < 4; ++kk) {
            #pragma unroll
            for (int f = 0; f < 4; ++f) {
                bf16x8 kf = *(const bf16x8*)&Ks[f * 16 + lo][kk * 32 + hi * 8];
                sv[0][f] = MFMA16(kf, qf[0][kk], sv[0][f]);
                sv[1][f] = MFMA16(kf, qf[1][kk], sv[1][f]);
            }
        }
        __builtin_amdgcn_s_setprio(0);

        #pragma unroll
        for (int g = 0; g < 2; ++g) {
            const int qg0 = q0 + wv * 32 + g * 16;
            if (kv0 + 63 > qg0) {
                int qg = qg0 + lo;
                #pragma unroll
                for (int f = 0; f < 4; ++f)
                    #pragma unroll
                    for (int i = 0; i < 4; ++i)
                        if (kv0 + f * 16 + hi * 4 + i > qg) sv[g][f][i] = -INFINITY;
            }
            float pm = -INFINITY;
            #pragma unroll
            for (int f = 0; f < 4; ++f)
                pm = fmaxf(pm, fmaxf(fmaxf(sv[g][f][0], sv[g][f][1]),
                                     fmaxf(sv[g][f][2], sv[g][f][3])));
            pm = fmaxf(pm, __shfl_xor(pm, 16));
            pm = fmaxf(pm, __shfl_xor(pm, 32));
            if (!__all(pm - M_[g] <= 8.f)) {
                float nM = fmaxf(M_[g], pm);
                float scn = EXP2F(M_[g] - nM);
                L_[g] *= scn;
                #pragma unroll
                for (int i = 0; i < 4; ++i) {
                    float si = __shfl(scn, (lane & 48) + hi * 4 + i);
                    #pragma unroll
                    for (int f = 0; f < 8; ++f) acc[g][f][i] *= si;
                }
                M_[g] = nM;
            }
            float rs = 0.f;
            #pragma unroll
            for (int f = 0; f < 4; ++f)
                #pragma unroll
                for (int i = 0; i < 4; ++i) {
                    float e = EXP2F(sv[g][f][i] - M_[g]);
                    sv[g][f][i] = e;
                    rs += e;
                }
            rs += __shfl_xor(rs, 16);
            rs += __shfl_xor(rs, 32);
            L_[g] += rs;
            #pragma unroll
            for (int f = 0; f < 4; ++f) {
                bf16x4 p;
                p[0] = (bf16)sv[g][f][0]; p[1] = (bf16)sv[g][f][1];
                p[2] = (bf16)sv[g][f][2]; p[3] = (bf16)sv[g][f][3];
                *(bf16x4*)&Ps[wv][g * 16 + lo][f * 16 + hi * 4] = p;
            }
        }
        __builtin_amdgcn_s_setprio(1);
        #pragma unroll
        for (int kk = 0; kk < 2; ++kk) {
            bf16x8 pa0 = *(const bf16x8*)&Ps[wv][lo][kk * 32 + hi * 8];
            bf16x8 pa1 = *(const bf16x8*)&Ps[wv][16 + lo][kk * 32 + hi * 8];
            #pragma unroll
            for (int f = 0; f < 8; ++f) {
                int row = f * 16 + lo;
                bf16x8 vf = *(const bf16x8*)&Vt[row][(kk * 32 + hi * 8) ^ ((row & 7) << 3)];
                acc[0][f] = MFMA16(pa0, vf, acc[0][f]);
                acc[1][f] = MFMA16(pa1, vf, acc[1][f]);
            }
        }
        __builtin_amdgcn_s_setprio(0);
    }
#undef ISSUE
    const size_t pb = ((size_t)b * CH + slot) * QB;
    #pragma unroll
    for (int g = 0; g < 2; ++g)
        #pragma unroll
        for (int f = 0; f < 8; ++f)
            #pragma unroll
            for (int i = 0; i < 4; ++i) {
                int row = wv * 32 + g * 16 + hi * 4 + i;
                Opart[(pb + row) * 128 + f * 16 + lo] = (bf16)acc[g][f][i];
            }
    if (hi == 0) {
        #pragma unroll
        for (int g = 0; g < 2; ++g) {
            Mpart[pb + wv * 32 + g * 16 + lo] = M_[g];
            Lpart[pb + wv * 32 + g * 16 + lo] = L_[g];
        }
    }
}

// ---------------------------------------------------------------------------
// Kernel 3: combine chunk partials (exp2 domain, bf16 partials).
// grid (NQB*2, B), block 256; each block handles a 128-row half of a q-block.
// ---------------------------------------------------------------------------
__global__ __launch_bounds__(256) void reduce_kernel(
    const bf16* __restrict__ Opart, const float* __restrict__ Mpart,
    const float* __restrict__ Lpart, float* __restrict__ out, int DIV, int CH)
{
    __shared__ float wexp[7][128];
    __shared__ float invL[128];
    const int qb = blockIdx.x >> 1, half = blockIdx.x & 1;
    const int b = blockIdx.y, t = threadIdx.x;
    const int r0 = half * 128;
    int pbase = 0, nact = 1;
    for (int j = 0; j <= qb; ++j) {
        int n = (4 * j + 4 + DIV - 1) / DIV;
        if (j == qb) { nact = n; break; }
        pbase += n;
    }
    const size_t pb = ((size_t)b * CH + pbase) * QB;
    if (t < 128) {
        float Mstar = -INFINITY;
        for (int c = 0; c < nact; ++c)
            Mstar = fmaxf(Mstar, Mpart[pb + c * QB + r0 + t]);
        float Ls = 0.f;
        for (int c = 0; c < nact; ++c) {
            float wc = __builtin_amdgcn_exp2f(Mpart[pb + c * QB + r0 + t] - Mstar);
            wexp[c][t] = wc;
            Ls += wc * Lpart[pb + c * QB + r0 + t];
        }
        invL[t] = 1.f / Ls;
    }
    __syncthreads();
    #pragma unroll
    for (int rep = 0; rep < 16; ++rep) {
        int idx = rep * 256 + t;
        int row = idx >> 5, c4 = (idx & 31) * 4;
        float ox = 0.f, oy = 0.f, oz = 0.f, ow = 0.f;
        for (int c = 0; c < nact; ++c) {
            float wc = wexp[c][row];
            bf16x4 v = *(const bf16x4*)(Opart + (pb + (size_t)c * QB + r0 + row) * 128 + c4);
            ox += wc * (float)v[0]; oy += wc * (float)v[1];
            oz += wc * (float)v[2]; ow += wc * (float)v[3];
        }
        float il = invL[row];
        float4 o = make_float4(ox * il, oy * il, oz * il, ow * il);
        *(float4*)(out + ((size_t)b * Ss + qb * QB + r0 + row) * 128 + c4) = o;
    }
}

extern "C" void kernel_launch(void* const* d_in, const int* in_sizes, int n_in,
                              void* d_out, int out_size, void* d_ws, size_t ws_size,
                              hipStream_t stream) {
    (void)in_sizes; (void)n_in; (void)out_size;
    const float* embds = (const float*)d_in[0];
    const float* Wq = (const float*)d_in[1];
    const float* bq = (const float*)d_in[2];
    const float* Wk = (const float*)d_in[3];
    const float* bk = (const float*)d_in[4];
    const float* Wv = (const float*)d_in[5];
    const float* bv = (const float*)d_in[6];

    char* ws = (char*)d_ws;
    size_t off = 0;
    bf16* Qb    = (bf16*)(ws + off); off += (size_t)Mrows * Hh * 2;
    bf16* Kb    = (bf16*)(ws + off); off += (size_t)Mrows * Hh * 2;
    bf16* Vtg   = (bf16*)(ws + off); off += (size_t)Mrows * Hh * 2;
    bf16* Wfrag = (bf16*)(ws + off); off += (size_t)3 * Hh * Ee * 2;

    auto chunks_for = [](int div) {
        int s = 0;
        for (int qb = 0; qb < NQB; ++qb) s += (4 * qb + 4 + div - 1) / div;
        return s;
    };
    auto need = [&](int ch) {
        return off + (size_t)Bb * ch * QB * 128 * 2 + (size_t)Bb * ch * QB * 8;
    };
    int DIV = 10;
    int CH = chunks_for(DIV);                     // 61
    if (need(CH) > ws_size) { DIV = 20; CH = chunks_for(DIV); }
    bf16* Opart = (bf16*)(ws + off);
    size_t osz = (size_t)Bb * CH * QB * 128 * 2;
    float* Mp = (float*)(ws + off + osz);
    float* Lp = Mp + (size_t)Bb * CH * QB;

    wfrag_kernel<<<dim3(24), 256, 0, stream>>>(Wq, Wk, Wv, Wfrag);
    proj_kernel<<<dim3(Mrows / 64), 512, 0, stream>>>(embds, Wfrag, bq, bk, bv, Qb, Kb, Vtg);
    attn_kernel<<<dim3(CH, Bb), 512, 0, stream>>>(Qb, Kb, Vtg, Opart, Mp, Lp, DIV, CH);
    reduce_kernel<<<dim3(NQB * 2, Bb), 256, 0, stream>>>(Opart, Mp, Lp, (float*)d_out, DIV, CH);
}